// Round 15
// baseline (523.058 us; speedup 1.0000x reference)
//
#include <hip/hip_runtime.h>
#include <hip/hip_bf16.h>
#include <math.h>

#define NB 4
#define IMG 192
#define HW (IMG*IMG)        // 36864
#define T_TOT (NB*HW)       // 147456
#define HID 512
#define NWB 2304            // total windows
#define WPB 576             // windows per batch
#define NWS 24              // windows per side

typedef __bf16 bf16;
typedef __bf16 bf8 __attribute__((ext_vector_type(8)));
typedef __bf16 bf4 __attribute__((ext_vector_type(4)));
typedef float f32x4 __attribute__((ext_vector_type(4)));

#define MFMA(a,b,c) __builtin_amdgcn_mfma_f32_16x16x32_bf16(a,b,c,0,0,0)

// Counted-wait barriers (avoid __syncthreads' vmcnt(0) drain).
#define BAR_LGKM asm volatile("s_waitcnt lgkmcnt(0)\ns_barrier" ::: "memory")
#define BAR_ALL  asm volatile("s_waitcnt vmcnt(0) lgkmcnt(0)\ns_barrier" ::: "memory")

__device__ __forceinline__ int swz128(int row, int col){ return row*128 + (col ^ ((row&7)<<3)); }

__device__ __forceinline__ bf8 zero_bf8(){
  bf8 z = { (bf16)0.f,(bf16)0.f,(bf16)0.f,(bf16)0.f,(bf16)0.f,(bf16)0.f,(bf16)0.f,(bf16)0.f };
  return z;
}
__device__ __forceinline__ f32x4 zero_f4(){ f32x4 z = {0.f,0.f,0.f,0.f}; return z; }

// async global->LDS DMA, 16B per lane; lds base is wave-uniform, HW adds lane*16
typedef const __attribute__((address_space(1))) unsigned int as1_u32;
typedef __attribute__((address_space(3))) unsigned int as3_u32;
__device__ __forceinline__ void gload16(const bf16* g, bf16* l){
  __builtin_amdgcn_global_load_lds((as1_u32*)g, (as3_u32*)l, 16, 0, 0);
}

// ---------------- kernel 0: merged weight prep (one launch) --------------
__global__ __launch_bounds__(256) void k_prep(
    const float* __restrict__ q_w, const float* __restrict__ kv_w,
    const float* __restrict__ proj_w, const float* __restrict__ fc1w,
    const float* __restrict__ fc2w, const float* __restrict__ mproj_w,
    const float* __restrict__ cor_w,
    bf16* __restrict__ wq, bf16* __restrict__ wkv, bf16* __restrict__ wpj,
    bf16* __restrict__ wf1, bf16* __restrict__ wf2, bf16* __restrict__ a2w)
{
  int idx = blockIdx.x*256 + threadIdx.x;
  if (idx < 16384){ wq[idx] = (bf16)(q_w[idx]*0.25f); return; }
  idx -= 16384;
  if (idx < 32768){ wkv[idx] = (bf16)kv_w[idx]; return; }
  idx -= 32768;
  if (idx < 16384){ wpj[idx] = (bf16)proj_w[idx]; return; }
  idx -= 16384;
  if (idx < 65536){ wf1[idx] = (bf16)fc1w[idx]; return; }
  idx -= 65536;
  if (idx < 65536){ wf2[idx] = (bf16)fc2w[idx]; return; }
  idx -= 65536;
  if (idx >= 4096) return;
  int o = idx >> 5, k = idx & 31;
  float acc = 0.f;
  if (k < 16){
    int h = k >> 1, c = k & 1;
    #pragma unroll
    for (int i=0;i<16;i++)
      acc += mproj_w[o*128 + h*16 + i] * cor_w[(h*16+i)*2 + c];
  }
  a2w[o*32 + k] = (bf16)acc;
}

// ---------------- kernel 2: fused LN1 + window attention (r14) -----------
__global__ __launch_bounds__(256) void k_attn(
    const float* __restrict__ x_in, const float* __restrict__ cor,
    const float* __restrict__ n1w, const float* __restrict__ n1b,
    const bf16* __restrict__ wq, const bf16* __restrict__ wkv,
    const bf16* __restrict__ wpj, const bf16* __restrict__ a2w,
    const float* __restrict__ proj_b, const float* __restrict__ mproj_b,
    float* __restrict__ x1, float* __restrict__ out_m)
{
  __shared__ __align__(16) bf16 s_s [64*128];
  __shared__ __align__(16) bf16 s_k [64*128];
  __shared__ __align__(16) bf16 s_vT[128*64];
  __shared__ __align__(16) bf16 s_P [64*64];
  __shared__ __align__(16) bf16 s_cT[16*64];
  __shared__ __align__(16) bf16 s_D [64*32];

  int tid = threadIdx.x, wm = tid>>6, l = tid&63;
  int lr = l & 15, lg = l >> 4;
  int win = blockIdx.x;
  int b  = win / WPB, wi = win % WPB;
  int wy = wi / NWS,  wx = wi % NWS;
  int bp = (b + NB/2) % NB;          // partner frame (same spatial window)

  float cwf = 0.f;
  if (tid < 128){
    int m = tid >> 1, c = tid & 1;
    cwf = cor[((size_t)b*HW + (size_t)(wy*8+(m>>3))*IMG + wx*8+(m&7))*2 + c];
  }

  *(unsigned long long*)&s_D[tid*8]   = 0ull;
  *(unsigned long long*)&s_D[tid*8+4] = 0ull;
  if (tid >= 192){
    int cc = tid - 192;
    #pragma unroll
    for (int r=3;r<16;r++) s_cT[r*64 + cc] = (bf16)0.f;
  }
  if (tid < 128){
    int c = tid & 1, m = tid >> 1;
    s_cT[c*64 + (m ^ (c<<3))] = (bf16)cwf;
  } else if (tid < 192){
    int m = tid - 128;
    s_cT[2*64 + (m ^ 16)] = (bf16)1.0f;
  }

  // ---- LN1(partner) -> s_s (own rows) ----
  {
    float4 nw0 = *(const float4*)(n1w + lr*8), nw1 = *(const float4*)(n1w + lr*8 + 4);
    float4 nb0 = *(const float4*)(n1b + lr*8), nb1 = *(const float4*)(n1b + lr*8 + 4);
    #pragma unroll
    for (int p=0;p<4;p++){
      int n = wm*16 + p*4 + lg;
      const float* xp = x_in + ((size_t)bp*HW + (size_t)(wy*8+(n>>3))*IMG + wx*8+(n&7))*128 + lr*8;
      float4 a = *(const float4*)xp;
      float4 b4 = *(const float4*)(xp+4);
      float s  = a.x+a.y+a.z+a.w + b4.x+b4.y+b4.z+b4.w;
      float sq = a.x*a.x+a.y*a.y+a.z*a.z+a.w*a.w + b4.x*b4.x+b4.y*b4.y+b4.z*b4.z+b4.w*b4.w;
      #pragma unroll
      for (int m=1;m<16;m<<=1){ s += __shfl_xor(s,m,16); sq += __shfl_xor(sq,m,16); }
      float mean = s*(1.f/128.f), var = sq*(1.f/128.f) - mean*mean;
      float rstd = rsqrtf(var + 1e-5f);
      bf8 o;
      o[0] = (bf16)((a.x -mean)*rstd*nw0.x + nb0.x);
      o[1] = (bf16)((a.y -mean)*rstd*nw0.y + nb0.y);
      o[2] = (bf16)((a.z -mean)*rstd*nw0.z + nb0.z);
      o[3] = (bf16)((a.w -mean)*rstd*nw0.w + nb0.w);
      o[4] = (bf16)((b4.x-mean)*rstd*nw1.x + nb1.x);
      o[5] = (bf16)((b4.y-mean)*rstd*nw1.y + nb1.y);
      o[6] = (bf16)((b4.z-mean)*rstd*nw1.z + nb1.z);
      o[7] = (bf16)((b4.w-mean)*rstd*nw1.w + nb1.w);
      *(bf8*)&s_s[swz128(n, lr*8)] = o;
    }
  }

  // ---- kv GEMM (A = own s_s rows) ----
  {
    bf8 af[4];
    #pragma unroll
    for (int ks=0;ks<4;ks++) af[ks] = *(const bf8*)&s_s[swz128(wm*16+lr, ks*32 + lg*8)];
    #pragma unroll
    for (int nt=0;nt<8;nt++){
      f32x4 acc = zero_f4();
      #pragma unroll
      for (int ks=0;ks<4;ks++){
        bf8 bfr = *(const bf8*)(wkv + (nt*16+lr)*128 + ks*32 + lg*8);
        acc = MFMA(af[ks], bfr, acc);
      }
      #pragma unroll
      for (int j=0;j<4;j++){
        int row = wm*16 + lg*4 + j;
        s_k[swz128(row, nt*16+lr)] = (bf16)acc[j];
      }
    }
    #pragma unroll
    for (int nt=0;nt<8;nt++){
      f32x4 acc = zero_f4();
      #pragma unroll
      for (int ks=0;ks<4;ks++){
        bf8 bfr = *(const bf8*)(wkv + (128 + nt*16+lr)*128 + ks*32 + lg*8);
        acc = MFMA(af[ks], bfr, acc);
      }
      #pragma unroll
      for (int j=0;j<4;j++){
        int tok = wm*16 + lg*4 + j;
        int chc = nt*16 + lr;
        s_vT[chc*64 + (tok ^ ((chc&7)<<3))] = (bf16)acc[j];
      }
    }
  }

  // ---- LN1(own) -> s_s (own rows) ----
  {
    float4 nw0 = *(const float4*)(n1w + lr*8), nw1 = *(const float4*)(n1w + lr*8 + 4);
    float4 nb0 = *(const float4*)(n1b + lr*8), nb1 = *(const float4*)(n1b + lr*8 + 4);
    #pragma unroll
    for (int p=0;p<4;p++){
      int n = wm*16 + p*4 + lg;
      const float* xp = x_in + ((size_t)b*HW + (size_t)(wy*8+(n>>3))*IMG + wx*8+(n&7))*128 + lr*8;
      float4 a = *(const float4*)xp;
      float4 b4 = *(const float4*)(xp+4);
      float s  = a.x+a.y+a.z+a.w + b4.x+b4.y+b4.z+b4.w;
      float sq = a.x*a.x+a.y*a.y+a.z*a.z+a.w*a.w + b4.x*b4.x+b4.y*b4.y+b4.z*b4.z+b4.w*b4.w;
      #pragma unroll
      for (int m=1;m<16;m<<=1){ s += __shfl_xor(s,m,16); sq += __shfl_xor(sq,m,16); }
      float mean = s*(1.f/128.f), var = sq*(1.f/128.f) - mean*mean;
      float rstd = rsqrtf(var + 1e-5f);
      bf8 o;
      o[0] = (bf16)((a.x -mean)*rstd*nw0.x + nb0.x);
      o[1] = (bf16)((a.y -mean)*rstd*nw0.y + nb0.y);
      o[2] = (bf16)((a.z -mean)*rstd*nw0.z + nb0.z);
      o[3] = (bf16)((a.w -mean)*rstd*nw0.w + nb0.w);
      o[4] = (bf16)((b4.x-mean)*rstd*nw1.x + nb1.x);
      o[5] = (bf16)((b4.y-mean)*rstd*nw1.y + nb1.y);
      o[6] = (bf16)((b4.z-mean)*rstd*nw1.z + nb1.z);
      o[7] = (bf16)((b4.w-mean)*rstd*nw1.w + nb1.w);
      *(bf8*)&s_s[swz128(n, lr*8)] = o;
    }
  }

  // ---- q GEMM in-place (own rows) ----
  {
    bf8 af[4];
    #pragma unroll
    for (int ks=0;ks<4;ks++) af[ks] = *(const bf8*)&s_s[swz128(wm*16+lr, ks*32 + lg*8)];
    #pragma unroll
    for (int nt=0;nt<8;nt++){
      f32x4 acc = zero_f4();
      #pragma unroll
      for (int ks=0;ks<4;ks++){
        bf8 bfr = *(const bf8*)(wq + (nt*16+lr)*128 + ks*32 + lg*8);
        acc = MFMA(af[ks], bfr, acc);
      }
      #pragma unroll
      for (int j=0;j<4;j++){
        int row = wm*16 + lg*4 + j;
        s_s[swz128(row, nt*16+lr)] = (bf16)acc[j];
      }
    }
  }

  BAR_LGKM;    // single sync: s_k/s_vT/s_cT visible to all waves

  float mycw[4] = {0.f,0.f,0.f,0.f};
  if (lr < 2){
    #pragma unroll
    for (int j=0;j<4;j++){
      int row = wm*16 + lg*4 + j;
      mycw[j] = (float)s_cT[lr*64 + (row ^ (lr<<3))];
    }
  }

  // ---- software-pipelined head loop ----
  f32x4 accS[4];
  {
    bf8 aS = zero_bf8();
    if (l < 32) aS = *(const bf8*)&s_s[swz128(wm*16+lr, lg*8)];
    #pragma unroll
    for (int nt=0;nt<4;nt++){
      bf8 bSv = zero_bf8();
      if (l < 32) bSv = *(const bf8*)&s_k[swz128(nt*16+lr, lg*8)];
      accS[nt] = MFMA(aS, bSv, zero_f4());
    }
  }
  #pragma unroll
  for (int h=0;h<8;h++){
    #pragma unroll
    for (int nt=0;nt<4;nt++){
      #pragma unroll
      for (int j=0;j<4;j++){
        int row = wm*16 + lg*4 + j;
        s_P[row*64 + ((nt*16+lr) ^ ((row&7)<<3))] = (bf16)__expf(accS[nt][j]);
      }
    }
    if (h < 7){
      bf8 aS = zero_bf8();
      if (l < 32) aS = *(const bf8*)&s_s[swz128(wm*16+lr, (h+1)*16 + lg*8)];
      #pragma unroll
      for (int nt=0;nt<4;nt++){
        bf8 bSv = zero_bf8();
        if (l < 32) bSv = *(const bf8*)&s_k[swz128(nt*16+lr, (h+1)*16 + lg*8)];
        accS[nt] = MFMA(aS, bSv, zero_f4());
      }
    }
    f32x4 accO = zero_f4(), accPC = zero_f4();
    #pragma unroll
    for (int ks=0;ks<2;ks++){
      int rowA = wm*16 + lr;
      bf8 aP = *(const bf8*)&s_P[rowA*64 + ((ks*32 + lg*8) ^ ((rowA&7)<<3))];
      int chc = h*16 + lr;
      bf8 bV = *(const bf8*)&s_vT[chc*64 + ((ks*32 + lg*8) ^ ((chc&7)<<3))];
      accO = MFMA(aP, bV, accO);
      bf8 bC = *(const bf8*)&s_cT[lr*64 + ((ks*32 + lg*8) ^ ((lr&7)<<3))];
      accPC = MFMA(aP, bC, accPC);
    }
    #pragma unroll
    for (int j=0;j<4;j++){
      int row = wm*16 + lg*4 + j;
      float rs = __shfl(accPC[j], (l & 48) + 2, 64);
      float inv = __builtin_amdgcn_rcpf(rs);
      s_s[swz128(row, h*16+lr)] = (bf16)(accO[j]*inv);
      if (lr < 2)
        s_D[row*32 + ((2*h+lr) ^ ((row&3)<<3))] = (bf16)(accPC[j]*inv - mycw[j]);
    }
  }

  // ---- proj (+residual) ----
  {
    bf8 af[4];
    #pragma unroll
    for (int ks=0;ks<4;ks++) af[ks] = *(const bf8*)&s_s[swz128(wm*16+lr, ks*32 + lg*8)];
    #pragma unroll
    for (int nt=0;nt<8;nt++){
      f32x4 acc = zero_f4();
      #pragma unroll
      for (int ks=0;ks<4;ks++){
        bf8 bfr = *(const bf8*)(wpj + (nt*16+lr)*128 + ks*32 + lg*8);
        acc = MFMA(af[ks], bfr, acc);
      }
      int col = nt*16 + lr;
      float pb = proj_b[col];
      #pragma unroll
      for (int j=0;j<4;j++){
        int tok = wm*16 + lg*4 + j;
        int yy = wy*8 + (tok>>3), xx = wx*8 + (tok&7);
        size_t addr = ((size_t)b*HW + yy*IMG + xx)*128 + col;
        x1[addr] = acc[j] + pb + x_in[addr];
      }
    }
  }
  // ---- motion ----
  {
    int rowA = wm*16 + lr;
    bf8 afD = *(const bf8*)&s_D[rowA*32 + ((lg*8) ^ ((rowA&3)<<3))];
    #pragma unroll
    for (int nt=0;nt<8;nt++){
      bf8 bfr = *(const bf8*)(a2w + (nt*16+lr)*32 + lg*8);
      f32x4 acc = MFMA(afD, bfr, zero_f4());
      int col = nt*16 + lr;
      float pb = mproj_b[col];
      #pragma unroll
      for (int j=0;j<4;j++){
        int tok = wm*16 + lg*4 + j;
        int yy = wy*8 + (tok>>3), xx = wx*8 + (tok&7);
        size_t addr = ((size_t)b*HW + yy*IMG + xx)*128 + col;
        out_m[addr] = acc[j] + pb;
      }
    }
  }
}

// ---------------- kernel 3: LN2 + fc1 (r9 structure) ---------------------
__global__ __launch_bounds__(256) void k_fc1(
    const float* __restrict__ x1, const float* __restrict__ n2w, const float* __restrict__ n2b,
    const bf16* __restrict__ wf1, const float* __restrict__ fc1b, bf16* __restrict__ h)
{
  __shared__ __align__(16) bf16 s_a[64*128];
  int tid = threadIdx.x, wm = tid>>6, l = tid&63;
  int lr = l & 15, lg = l >> 4;
  size_t t0 = (size_t)blockIdx.x * 64;

  float4 nw0 = *(const float4*)(n2w + lr*8), nw1 = *(const float4*)(n2w + lr*8 + 4);
  float4 nb0 = *(const float4*)(n2b + lr*8), nb1 = *(const float4*)(n2b + lr*8 + 4);

  #pragma unroll
  for (int rr=0; rr<4; rr++){
    int row = wm*16 + rr*4 + lg;
    const float* xp = x1 + (t0+row)*128 + lr*8;
    float4 a = *(const float4*)xp;
    float4 b4 = *(const float4*)(xp+4);
    float s  = a.x+a.y+a.z+a.w + b4.x+b4.y+b4.z+b4.w;
    float sq = a.x*a.x+a.y*a.y+a.z*a.z+a.w*a.w + b4.x*b4.x+b4.y*b4.y+b4.z*b4.z+b4.w*b4.w;
    #pragma unroll
    for (int m=1;m<16;m<<=1){ s += __shfl_xor(s,m,16); sq += __shfl_xor(sq,m,16); }
    float mean = s*(1.f/128.f), var = sq*(1.f/128.f) - mean*mean;
    float rstd = rsqrtf(var + 1e-5f);
    bf8 o;
    o[0] = (bf16)((a.x -mean)*rstd*nw0.x + nb0.x);
    o[1] = (bf16)((a.y -mean)*rstd*nw0.y + nb0.y);
    o[2] = (bf16)((a.z -mean)*rstd*nw0.z + nb0.z);
    o[3] = (bf16)((a.w -mean)*rstd*nw0.w + nb0.w);
    o[4] = (bf16)((b4.x-mean)*rstd*nw1.x + nb1.x);
    o[5] = (bf16)((b4.y-mean)*rstd*nw1.y + nb1.y);
    o[6] = (bf16)((b4.z-mean)*rstd*nw1.z + nb1.z);
    o[7] = (bf16)((b4.w-mean)*rstd*nw1.w + nb1.w);
    *(bf8*)&s_a[swz128(row, lr*8)] = o;
  }
  __syncthreads();

  bf8 af[4];
  #pragma unroll
  for (int ks=0;ks<4;ks++) af[ks] = *(const bf8*)&s_a[swz128(wm*16+lr, ks*32 + lg*8)];
  for (int ntb=0; ntb<4; ntb++){
    f32x4 acc[8];
    #pragma unroll
    for (int q8=0;q8<8;q8++){
      acc[q8] = zero_f4();
      #pragma unroll
      for (int ks=0;ks<4;ks++){
        int ocol = ntb*128 + q8*16 + lr;
        bf8 bfr = *(const bf8*)(wf1 + (size_t)ocol*128 + ks*32 + lg*8);
        acc[q8] = MFMA(af[ks], bfr, acc[q8]);
      }
    }
    #pragma unroll
    for (int q8=0;q8<8;q8++){
      int col = ntb*128 + q8*16 + lr;
      float bb = fc1b[col];
      #pragma unroll
      for (int j=0;j<4;j++){
        int tl = wm*16 + lg*4 + j;
        h[(t0+tl)*512 + col] = (bf16)(acc[q8][j] + bb);
      }
    }
  }
}

// ---------------- kernel 4: dwconv3x3 + GELU + fc2 + residual ------------
// r12 DMA double-buffer + counted barriers, PLUS conv weights staged in LDS
// once at start. Rationale (vmcnt retires IN ORDER): any global weight load
// issued after the prefetch DMA forces the DMA to complete at that weight's
// first use. With dww/dwb in LDS, the only in-kc vmem after the DMA is fc2's
// wf2 loads, whose first use is after conv+GELU -> prefetch finally spans
// most of the kc body.
__global__ __launch_bounds__(256) void k_mlp2(
    const bf16* __restrict__ h, const float* __restrict__ dww, const float* __restrict__ dwb,
    const bf16* __restrict__ wf2, const float* __restrict__ fc2b,
    const float* __restrict__ x1, float* __restrict__ outx)
{
  __shared__ __align__(16) bf16 s_hh[2][100*128];   // 51200 B
  __shared__ __align__(16) float s_w[4608];         // dww (512x9 f32), 18432 B
  __shared__ __align__(16) float s_b[512];          // dwb, 2048 B
  int tid = threadIdx.x, wm = tid>>6, l = tid&63;
  int lr = l & 15, lg = l >> 4;
  int tile = 575 - blockIdx.x, b = 3 - blockIdx.y;   // LIFO vs producer order
  int ty = tile / 24, tx = tile % 24;
  int cq = (tid & 31) * 4;     // channel quad
  int tg2 = tid >> 5;          // output row iy (0..7)

  f32x4 acc[8];
  #pragma unroll
  for (int q=0;q<8;q++) acc[q] = zero_f4();

  // ---- one-time: conv weights -> LDS (global loads BEFORE any DMA) ----
  #pragma unroll
  for (int i=0;i<18;i++){
    int idx = i*256 + tid;
    if (idx < 4608) s_w[idx] = dww[idx];
  }
  #pragma unroll
  for (int i=0;i<2;i++){
    int idx = i*256 + tid;
    if (idx < 512) s_b[idx] = dwb[idx];
  }

  // ---- one-time: zero OOB halo slots in BOTH buffers (edge tiles only) ----
  bool edge = (ty==0) | (ty==23) | (tx==0) | (tx==23);
  if (edge){
    #pragma unroll
    for (int it=0; it<7; it++){
      int idx = it*256 + tid;
      if (idx < 1600){
        int pos = idx>>4, c0 = (idx&15)*8;
        int hy = pos/10, hx = pos%10;
        int yy = ty*8 + hy - 1, xx = tx*8 + hx - 1;
        if (yy<0 || yy>=IMG || xx<0 || xx>=IMG){
          *(bf8*)&s_hh[0][pos*128 + c0] = zero_bf8();
          *(bf8*)&s_hh[1][pos*128 + c0] = zero_bf8();
        }
      }
    }
  }

  #define STAGE_DMA(KC, BUF)                                                  \
    _Pragma("unroll")                                                         \
    for (int it=0; it<7; it++){                                               \
      int idx = it*256 + tid;                                                 \
      if (idx < 1600){                                                        \
        int pos = idx>>4, c0 = (idx&15)*8;                                    \
        int hy = pos/10, hx = pos%10;                                         \
        int yy = ty*8 + hy - 1, xx = tx*8 + hx - 1;                           \
        bf16* lb = &s_hh[BUF][it*2048 + wm*512];  /* wave-uniform base */     \
        if (yy>=0 && yy<IMG && xx>=0 && xx<IMG)                               \
          gload16(h + ((size_t)b*HW + yy*IMG + xx)*512 + (KC)*128 + c0, lb);  \
      }                                                                       \
    }

  STAGE_DMA(0, 0);
  BAR_ALL;                     // buf0 staged + weights/zeros visible

  int cur = 0;
  for (int kc=0;kc<4;kc++){
    if (kc < 3) STAGE_DMA(kc+1, cur^1);   // async into the free buffer

    // ---- depthwise conv, weights from LDS (no vmcnt traffic) ----
    int chg0 = kc*128 + cq;
    float4 bias4 = *(const float4*)&s_b[chg0];
    float cr[8][4];
    #pragma unroll
    for (int i=0;i<8;i++){ cr[i][0]=bias4.x; cr[i][1]=bias4.y; cr[i][2]=bias4.z; cr[i][3]=bias4.w; }
    #pragma unroll
    for (int dy=0;dy<3;dy++){
      float rv[10][4];
      #pragma unroll
      for (int p=0;p<10;p++){
        bf4 pv = *(const bf4*)&s_hh[cur][((tg2+dy)*10 + p)*128 + cq];
        rv[p][0]=(float)pv[0]; rv[p][1]=(float)pv[1];
        rv[p][2]=(float)pv[2]; rv[p][3]=(float)pv[3];
      }
      #pragma unroll
      for (int dx=0;dx<3;dx++){
        int tq = dy*3+dx;
        float w0 = s_w[(chg0+0)*9 + tq];
        float w1 = s_w[(chg0+1)*9 + tq];
        float w2 = s_w[(chg0+2)*9 + tq];
        float w3 = s_w[(chg0+3)*9 + tq];
        #pragma unroll
        for (int i=0;i<8;i++){
          cr[i][0] += rv[i+dx][0]*w0;
          cr[i][1] += rv[i+dx][1]*w1;
          cr[i][2] += rv[i+dx][2]*w2;
          cr[i][3] += rv[i+dx][3]*w3;
        }
      }
    }
    // ---- GELU (tanh form, register-only) ----
    bf4 gout[8];
    #pragma unroll
    for (int i=0;i<8;i++){
      #pragma unroll
      for (int c=0;c<4;c++){
        float hv = cr[i][c];
        float hv2 = hv*hv;
        float v = hv * fmaf(hv2, -0.0713548353f, -1.5957691216f);
        float g = hv * __builtin_amdgcn_rcpf(1.0f + __expf(v));
        gout[i][c] = (bf16)g;
      }
    }
    BAR_LGKM;                  // conv reads done; DMA stays in flight
    #pragma unroll
    for (int i=0;i<8;i++){
      int pos = (tg2+1)*10 + (i+1);
      *(bf4*)&s_hh[cur][pos*128 + (cq ^ (i<<3))] = gout[i];
    }
    // ---- fc2 partial GEMM (first wf2 use is the only vmcnt drain point) ----
    {
      bf8 af[4];
      #pragma unroll
      for (int ks=0;ks<4;ks++){
        int tok = wm*16 + lr;
        int pos = ((tok>>3)+1)*10 + (tok&7) + 1;
        af[ks] = *(const bf8*)&s_hh[cur][pos*128 + ((ks*32 + lg*8) ^ ((lr&7)<<3))];
      }
      #pragma unroll
      for (int q=0;q<8;q++){
        #pragma unroll
        for (int ks=0;ks<4;ks++){
          bf8 bfr = *(const bf8*)(wf2 + (size_t)(q*16+lr)*512 + kc*128 + ks*32 + lg*8);
          acc[q] = MFMA(af[ks], bfr, acc[q]);
        }
      }
    }
    BAR_ALL;                   // fc2 reads done + next buffer's DMA landed
    cur ^= 1;
  }
  #pragma unroll
  for (int q=0;q<8;q++){
    int col = q*16 + lr;
    float bb = fc2b[col];
    #pragma unroll
    for (int j=0;j<4;j++){
      int tok = wm*16 + lg*4 + j;
      int yy = ty*8 + (tok>>3), xx = tx*8 + (tok&7);
      size_t addr = ((size_t)b*HW + yy*IMG + xx)*128 + col;
      outx[addr] = acc[q][j] + bb + x1[addr];
    }
  }
  #undef STAGE_DMA
}

// ---------------- launcher ----------------
extern "C" void kernel_launch(void* const* d_in, const int* in_sizes, int n_in,
                              void* d_out, int out_size, void* d_ws, size_t ws_size,
                              hipStream_t stream)
{
  const float* x      = (const float*)d_in[0];
  const float* cor    = (const float*)d_in[1];
  const float* q_w    = (const float*)d_in[2];
  const float* kv_w   = (const float*)d_in[3];
  const float* cor_w  = (const float*)d_in[4];
  const float* proj_w = (const float*)d_in[5];
  const float* proj_b = (const float*)d_in[6];
  const float* mproj_w= (const float*)d_in[7];
  const float* mproj_b= (const float*)d_in[8];
  const float* n1w    = (const float*)d_in[9];
  const float* n1b    = (const float*)d_in[10];
  const float* n2w    = (const float*)d_in[11];
  const float* n2b    = (const float*)d_in[12];
  const float* fc1w   = (const float*)d_in[13];
  const float* fc1b   = (const float*)d_in[14];
  const float* dww    = (const float*)d_in[15];
  const float* dwb    = (const float*)d_in[16];
  const float* fc2w   = (const float*)d_in[17];
  const float* fc2b   = (const float*)d_in[18];
  float* out = (float*)d_out;

  char* ws = (char*)d_ws;
  bf16* wq   = (bf16*)(ws + 0);          // 32768
  bf16* wkv  = (bf16*)(ws + 32768);      // 65536
  bf16* wpj  = (bf16*)(ws + 98304);      // 32768
  bf16* a2w  = (bf16*)(ws + 131072);     // 8192
  bf16* wf1  = (bf16*)(ws + 139264);     // 131072
  bf16* wf2  = (bf16*)(ws + 270336);     // 131072
  float* x1  = (float*)(ws + 401408);    // 75497472
  bf16* hbuf = (bf16*)(ws + 401408 + 75497472);  // 150994944

  k_prep<<<784, 256, 0, stream>>>(q_w, kv_w, proj_w, fc1w, fc2w, mproj_w, cor_w,
                                  wq, wkv, wpj, wf1, wf2, a2w);

  k_attn<<<NWB,      256, 0, stream>>>(x, cor, n1w, n1b, wq, wkv, wpj, a2w,
                                       proj_b, mproj_b,
                                       x1, out + (size_t)T_TOT*128);
  k_fc1 <<<T_TOT/64, 256, 0, stream>>>(x1, n2w, n2b, wf1, fc1b, hbuf);
  k_mlp2<<<dim3(576,4), 256, 0, stream>>>(hbuf, dww, dwb, wf2, fc2b, x1, out);
}

// Round 16
// 508.060 us; speedup vs baseline: 1.0295x; 1.0295x over previous
//
#include <hip/hip_runtime.h>
#include <hip/hip_bf16.h>
#include <math.h>

#define NB 4
#define IMG 192
#define HW (IMG*IMG)        // 36864
#define T_TOT (NB*HW)       // 147456
#define HID 512
#define NWB 2304            // total windows
#define WPB 576             // windows per batch
#define NWS 24              // windows per side

typedef __bf16 bf16;
typedef __bf16 bf8 __attribute__((ext_vector_type(8)));
typedef __bf16 bf4 __attribute__((ext_vector_type(4)));
typedef float f32x4 __attribute__((ext_vector_type(4)));

#define MFMA(a,b,c) __builtin_amdgcn_mfma_f32_16x16x32_bf16(a,b,c,0,0,0)

// Counted-wait barriers (avoid __syncthreads' vmcnt(0) drain).
#define BAR_LGKM asm volatile("s_waitcnt lgkmcnt(0)\ns_barrier" ::: "memory")
#define BAR_ALL  asm volatile("s_waitcnt vmcnt(0) lgkmcnt(0)\ns_barrier" ::: "memory")

__device__ __forceinline__ int swz128(int row, int col){ return row*128 + (col ^ ((row&7)<<3)); }

__device__ __forceinline__ bf8 zero_bf8(){
  bf8 z = { (bf16)0.f,(bf16)0.f,(bf16)0.f,(bf16)0.f,(bf16)0.f,(bf16)0.f,(bf16)0.f,(bf16)0.f };
  return z;
}
__device__ __forceinline__ f32x4 zero_f4(){ f32x4 z = {0.f,0.f,0.f,0.f}; return z; }

// async global->LDS DMA, 16B per lane; lds base is wave-uniform, HW adds lane*16
typedef const __attribute__((address_space(1))) unsigned int as1_u32;
typedef __attribute__((address_space(3))) unsigned int as3_u32;
__device__ __forceinline__ void gload16(const bf16* g, bf16* l){
  __builtin_amdgcn_global_load_lds((as1_u32*)g, (as3_u32*)l, 16, 0, 0);
}

// ---------------- kernel 0: merged weight prep (one launch) --------------
__global__ __launch_bounds__(256) void k_prep(
    const float* __restrict__ q_w, const float* __restrict__ kv_w,
    const float* __restrict__ proj_w, const float* __restrict__ fc1w,
    const float* __restrict__ fc2w, const float* __restrict__ mproj_w,
    const float* __restrict__ cor_w,
    bf16* __restrict__ wq, bf16* __restrict__ wkv, bf16* __restrict__ wpj,
    bf16* __restrict__ wf1, bf16* __restrict__ wf2, bf16* __restrict__ a2w)
{
  int idx = blockIdx.x*256 + threadIdx.x;
  if (idx < 16384){ wq[idx] = (bf16)(q_w[idx]*0.25f); return; }
  idx -= 16384;
  if (idx < 32768){ wkv[idx] = (bf16)kv_w[idx]; return; }
  idx -= 32768;
  if (idx < 16384){ wpj[idx] = (bf16)proj_w[idx]; return; }
  idx -= 16384;
  if (idx < 65536){ wf1[idx] = (bf16)fc1w[idx]; return; }
  idx -= 65536;
  if (idx < 65536){ wf2[idx] = (bf16)fc2w[idx]; return; }
  idx -= 65536;
  if (idx >= 4096) return;
  int o = idx >> 5, k = idx & 31;
  float acc = 0.f;
  if (k < 16){
    int h = k >> 1, c = k & 1;
    #pragma unroll
    for (int i=0;i<16;i++)
      acc += mproj_w[o*128 + h*16 + i] * cor_w[(h*16+i)*2 + c];
  }
  a2w[o*32 + k] = (bf16)acc;
}

// ---------------- kernel 2: fused LN1 + window attention (r14) -----------
// x1 now stored bf16 (was f32): halves x1 write traffic here and read
// traffic in k_fc1/k_mlp2. absmax budget: +~0.02 (threshold 0.109).
__global__ __launch_bounds__(256) void k_attn(
    const float* __restrict__ x_in, const float* __restrict__ cor,
    const float* __restrict__ n1w, const float* __restrict__ n1b,
    const bf16* __restrict__ wq, const bf16* __restrict__ wkv,
    const bf16* __restrict__ wpj, const bf16* __restrict__ a2w,
    const float* __restrict__ proj_b, const float* __restrict__ mproj_b,
    bf16* __restrict__ x1, float* __restrict__ out_m)
{
  __shared__ __align__(16) bf16 s_s [64*128];
  __shared__ __align__(16) bf16 s_k [64*128];
  __shared__ __align__(16) bf16 s_vT[128*64];
  __shared__ __align__(16) bf16 s_P [64*64];
  __shared__ __align__(16) bf16 s_cT[16*64];
  __shared__ __align__(16) bf16 s_D [64*32];

  int tid = threadIdx.x, wm = tid>>6, l = tid&63;
  int lr = l & 15, lg = l >> 4;
  int win = blockIdx.x;
  int b  = win / WPB, wi = win % WPB;
  int wy = wi / NWS,  wx = wi % NWS;
  int bp = (b + NB/2) % NB;          // partner frame (same spatial window)

  float cwf = 0.f;
  if (tid < 128){
    int m = tid >> 1, c = tid & 1;
    cwf = cor[((size_t)b*HW + (size_t)(wy*8+(m>>3))*IMG + wx*8+(m&7))*2 + c];
  }

  *(unsigned long long*)&s_D[tid*8]   = 0ull;
  *(unsigned long long*)&s_D[tid*8+4] = 0ull;
  if (tid >= 192){
    int cc = tid - 192;
    #pragma unroll
    for (int r=3;r<16;r++) s_cT[r*64 + cc] = (bf16)0.f;
  }
  if (tid < 128){
    int c = tid & 1, m = tid >> 1;
    s_cT[c*64 + (m ^ (c<<3))] = (bf16)cwf;
  } else if (tid < 192){
    int m = tid - 128;
    s_cT[2*64 + (m ^ 16)] = (bf16)1.0f;
  }

  // ---- LN1(partner) -> s_s (own rows) ----
  {
    float4 nw0 = *(const float4*)(n1w + lr*8), nw1 = *(const float4*)(n1w + lr*8 + 4);
    float4 nb0 = *(const float4*)(n1b + lr*8), nb1 = *(const float4*)(n1b + lr*8 + 4);
    #pragma unroll
    for (int p=0;p<4;p++){
      int n = wm*16 + p*4 + lg;
      const float* xp = x_in + ((size_t)bp*HW + (size_t)(wy*8+(n>>3))*IMG + wx*8+(n&7))*128 + lr*8;
      float4 a = *(const float4*)xp;
      float4 b4 = *(const float4*)(xp+4);
      float s  = a.x+a.y+a.z+a.w + b4.x+b4.y+b4.z+b4.w;
      float sq = a.x*a.x+a.y*a.y+a.z*a.z+a.w*a.w + b4.x*b4.x+b4.y*b4.y+b4.z*b4.z+b4.w*b4.w;
      #pragma unroll
      for (int m=1;m<16;m<<=1){ s += __shfl_xor(s,m,16); sq += __shfl_xor(sq,m,16); }
      float mean = s*(1.f/128.f), var = sq*(1.f/128.f) - mean*mean;
      float rstd = rsqrtf(var + 1e-5f);
      bf8 o;
      o[0] = (bf16)((a.x -mean)*rstd*nw0.x + nb0.x);
      o[1] = (bf16)((a.y -mean)*rstd*nw0.y + nb0.y);
      o[2] = (bf16)((a.z -mean)*rstd*nw0.z + nb0.z);
      o[3] = (bf16)((a.w -mean)*rstd*nw0.w + nb0.w);
      o[4] = (bf16)((b4.x-mean)*rstd*nw1.x + nb1.x);
      o[5] = (bf16)((b4.y-mean)*rstd*nw1.y + nb1.y);
      o[6] = (bf16)((b4.z-mean)*rstd*nw1.z + nb1.z);
      o[7] = (bf16)((b4.w-mean)*rstd*nw1.w + nb1.w);
      *(bf8*)&s_s[swz128(n, lr*8)] = o;
    }
  }

  // ---- kv GEMM (A = own s_s rows) ----
  {
    bf8 af[4];
    #pragma unroll
    for (int ks=0;ks<4;ks++) af[ks] = *(const bf8*)&s_s[swz128(wm*16+lr, ks*32 + lg*8)];
    #pragma unroll
    for (int nt=0;nt<8;nt++){
      f32x4 acc = zero_f4();
      #pragma unroll
      for (int ks=0;ks<4;ks++){
        bf8 bfr = *(const bf8*)(wkv + (nt*16+lr)*128 + ks*32 + lg*8);
        acc = MFMA(af[ks], bfr, acc);
      }
      #pragma unroll
      for (int j=0;j<4;j++){
        int row = wm*16 + lg*4 + j;
        s_k[swz128(row, nt*16+lr)] = (bf16)acc[j];
      }
    }
    #pragma unroll
    for (int nt=0;nt<8;nt++){
      f32x4 acc = zero_f4();
      #pragma unroll
      for (int ks=0;ks<4;ks++){
        bf8 bfr = *(const bf8*)(wkv + (128 + nt*16+lr)*128 + ks*32 + lg*8);
        acc = MFMA(af[ks], bfr, acc);
      }
      #pragma unroll
      for (int j=0;j<4;j++){
        int tok = wm*16 + lg*4 + j;
        int chc = nt*16 + lr;
        s_vT[chc*64 + (tok ^ ((chc&7)<<3))] = (bf16)acc[j];
      }
    }
  }

  // ---- LN1(own) -> s_s (own rows) ----
  {
    float4 nw0 = *(const float4*)(n1w + lr*8), nw1 = *(const float4*)(n1w + lr*8 + 4);
    float4 nb0 = *(const float4*)(n1b + lr*8), nb1 = *(const float4*)(n1b + lr*8 + 4);
    #pragma unroll
    for (int p=0;p<4;p++){
      int n = wm*16 + p*4 + lg;
      const float* xp = x_in + ((size_t)b*HW + (size_t)(wy*8+(n>>3))*IMG + wx*8+(n&7))*128 + lr*8;
      float4 a = *(const float4*)xp;
      float4 b4 = *(const float4*)(xp+4);
      float s  = a.x+a.y+a.z+a.w + b4.x+b4.y+b4.z+b4.w;
      float sq = a.x*a.x+a.y*a.y+a.z*a.z+a.w*a.w + b4.x*b4.x+b4.y*b4.y+b4.z*b4.z+b4.w*b4.w;
      #pragma unroll
      for (int m=1;m<16;m<<=1){ s += __shfl_xor(s,m,16); sq += __shfl_xor(sq,m,16); }
      float mean = s*(1.f/128.f), var = sq*(1.f/128.f) - mean*mean;
      float rstd = rsqrtf(var + 1e-5f);
      bf8 o;
      o[0] = (bf16)((a.x -mean)*rstd*nw0.x + nb0.x);
      o[1] = (bf16)((a.y -mean)*rstd*nw0.y + nb0.y);
      o[2] = (bf16)((a.z -mean)*rstd*nw0.z + nb0.z);
      o[3] = (bf16)((a.w -mean)*rstd*nw0.w + nb0.w);
      o[4] = (bf16)((b4.x-mean)*rstd*nw1.x + nb1.x);
      o[5] = (bf16)((b4.y-mean)*rstd*nw1.y + nb1.y);
      o[6] = (bf16)((b4.z-mean)*rstd*nw1.z + nb1.z);
      o[7] = (bf16)((b4.w-mean)*rstd*nw1.w + nb1.w);
      *(bf8*)&s_s[swz128(n, lr*8)] = o;
    }
  }

  // ---- q GEMM in-place (own rows) ----
  {
    bf8 af[4];
    #pragma unroll
    for (int ks=0;ks<4;ks++) af[ks] = *(const bf8*)&s_s[swz128(wm*16+lr, ks*32 + lg*8)];
    #pragma unroll
    for (int nt=0;nt<8;nt++){
      f32x4 acc = zero_f4();
      #pragma unroll
      for (int ks=0;ks<4;ks++){
        bf8 bfr = *(const bf8*)(wq + (nt*16+lr)*128 + ks*32 + lg*8);
        acc = MFMA(af[ks], bfr, acc);
      }
      #pragma unroll
      for (int j=0;j<4;j++){
        int row = wm*16 + lg*4 + j;
        s_s[swz128(row, nt*16+lr)] = (bf16)acc[j];
      }
    }
  }

  BAR_LGKM;    // single sync: s_k/s_vT/s_cT visible to all waves

  float mycw[4] = {0.f,0.f,0.f,0.f};
  if (lr < 2){
    #pragma unroll
    for (int j=0;j<4;j++){
      int row = wm*16 + lg*4 + j;
      mycw[j] = (float)s_cT[lr*64 + (row ^ (lr<<3))];
    }
  }

  // ---- software-pipelined head loop ----
  f32x4 accS[4];
  {
    bf8 aS = zero_bf8();
    if (l < 32) aS = *(const bf8*)&s_s[swz128(wm*16+lr, lg*8)];
    #pragma unroll
    for (int nt=0;nt<4;nt++){
      bf8 bSv = zero_bf8();
      if (l < 32) bSv = *(const bf8*)&s_k[swz128(nt*16+lr, lg*8)];
      accS[nt] = MFMA(aS, bSv, zero_f4());
    }
  }
  #pragma unroll
  for (int h=0;h<8;h++){
    #pragma unroll
    for (int nt=0;nt<4;nt++){
      #pragma unroll
      for (int j=0;j<4;j++){
        int row = wm*16 + lg*4 + j;
        s_P[row*64 + ((nt*16+lr) ^ ((row&7)<<3))] = (bf16)__expf(accS[nt][j]);
      }
    }
    if (h < 7){
      bf8 aS = zero_bf8();
      if (l < 32) aS = *(const bf8*)&s_s[swz128(wm*16+lr, (h+1)*16 + lg*8)];
      #pragma unroll
      for (int nt=0;nt<4;nt++){
        bf8 bSv = zero_bf8();
        if (l < 32) bSv = *(const bf8*)&s_k[swz128(nt*16+lr, (h+1)*16 + lg*8)];
        accS[nt] = MFMA(aS, bSv, zero_f4());
      }
    }
    f32x4 accO = zero_f4(), accPC = zero_f4();
    #pragma unroll
    for (int ks=0;ks<2;ks++){
      int rowA = wm*16 + lr;
      bf8 aP = *(const bf8*)&s_P[rowA*64 + ((ks*32 + lg*8) ^ ((rowA&7)<<3))];
      int chc = h*16 + lr;
      bf8 bV = *(const bf8*)&s_vT[chc*64 + ((ks*32 + lg*8) ^ ((chc&7)<<3))];
      accO = MFMA(aP, bV, accO);
      bf8 bC = *(const bf8*)&s_cT[lr*64 + ((ks*32 + lg*8) ^ ((lr&7)<<3))];
      accPC = MFMA(aP, bC, accPC);
    }
    #pragma unroll
    for (int j=0;j<4;j++){
      int row = wm*16 + lg*4 + j;
      float rs = __shfl(accPC[j], (l & 48) + 2, 64);
      float inv = __builtin_amdgcn_rcpf(rs);
      s_s[swz128(row, h*16+lr)] = (bf16)(accO[j]*inv);
      if (lr < 2)
        s_D[row*32 + ((2*h+lr) ^ ((row&3)<<3))] = (bf16)(accPC[j]*inv - mycw[j]);
    }
  }

  // ---- proj (+residual) -> x1 (bf16) ----
  {
    bf8 af[4];
    #pragma unroll
    for (int ks=0;ks<4;ks++) af[ks] = *(const bf8*)&s_s[swz128(wm*16+lr, ks*32 + lg*8)];
    #pragma unroll
    for (int nt=0;nt<8;nt++){
      f32x4 acc = zero_f4();
      #pragma unroll
      for (int ks=0;ks<4;ks++){
        bf8 bfr = *(const bf8*)(wpj + (nt*16+lr)*128 + ks*32 + lg*8);
        acc = MFMA(af[ks], bfr, acc);
      }
      int col = nt*16 + lr;
      float pb = proj_b[col];
      #pragma unroll
      for (int j=0;j<4;j++){
        int tok = wm*16 + lg*4 + j;
        int yy = wy*8 + (tok>>3), xx = wx*8 + (tok&7);
        size_t addr = ((size_t)b*HW + yy*IMG + xx)*128 + col;
        x1[addr] = (bf16)(acc[j] + pb + x_in[addr]);
      }
    }
  }
  // ---- motion ----
  {
    int rowA = wm*16 + lr;
    bf8 afD = *(const bf8*)&s_D[rowA*32 + ((lg*8) ^ ((rowA&3)<<3))];
    #pragma unroll
    for (int nt=0;nt<8;nt++){
      bf8 bfr = *(const bf8*)(a2w + (nt*16+lr)*32 + lg*8);
      f32x4 acc = MFMA(afD, bfr, zero_f4());
      int col = nt*16 + lr;
      float pb = mproj_b[col];
      #pragma unroll
      for (int j=0;j<4;j++){
        int tok = wm*16 + lg*4 + j;
        int yy = wy*8 + (tok>>3), xx = wx*8 + (tok&7);
        size_t addr = ((size_t)b*HW + yy*IMG + xx)*128 + col;
        out_m[addr] = acc[j] + pb;
      }
    }
  }
}

// ---------------- kernel 3: LN2 + fc1 (x1 bf16 input) --------------------
__global__ __launch_bounds__(256) void k_fc1(
    const bf16* __restrict__ x1, const float* __restrict__ n2w, const float* __restrict__ n2b,
    const bf16* __restrict__ wf1, const float* __restrict__ fc1b, bf16* __restrict__ h)
{
  __shared__ __align__(16) bf16 s_a[64*128];
  int tid = threadIdx.x, wm = tid>>6, l = tid&63;
  int lr = l & 15, lg = l >> 4;
  size_t t0 = (size_t)blockIdx.x * 64;

  float4 nw0 = *(const float4*)(n2w + lr*8), nw1 = *(const float4*)(n2w + lr*8 + 4);
  float4 nb0 = *(const float4*)(n2b + lr*8), nb1 = *(const float4*)(n2b + lr*8 + 4);

  #pragma unroll
  for (int rr=0; rr<4; rr++){
    int row = wm*16 + rr*4 + lg;
    bf8 v = *(const bf8*)(x1 + (t0+row)*128 + lr*8);
    float xv8[8];
    #pragma unroll
    for (int k=0;k<8;k++) xv8[k] = (float)v[k];
    float s=0.f, sq=0.f;
    #pragma unroll
    for (int k=0;k<8;k++){ s += xv8[k]; sq += xv8[k]*xv8[k]; }
    #pragma unroll
    for (int m=1;m<16;m<<=1){ s += __shfl_xor(s,m,16); sq += __shfl_xor(sq,m,16); }
    float mean = s*(1.f/128.f), var = sq*(1.f/128.f) - mean*mean;
    float rstd = rsqrtf(var + 1e-5f);
    bf8 o;
    o[0] = (bf16)((xv8[0]-mean)*rstd*nw0.x + nb0.x);
    o[1] = (bf16)((xv8[1]-mean)*rstd*nw0.y + nb0.y);
    o[2] = (bf16)((xv8[2]-mean)*rstd*nw0.z + nb0.z);
    o[3] = (bf16)((xv8[3]-mean)*rstd*nw0.w + nb0.w);
    o[4] = (bf16)((xv8[4]-mean)*rstd*nw1.x + nb1.x);
    o[5] = (bf16)((xv8[5]-mean)*rstd*nw1.y + nb1.y);
    o[6] = (bf16)((xv8[6]-mean)*rstd*nw1.z + nb1.z);
    o[7] = (bf16)((xv8[7]-mean)*rstd*nw1.w + nb1.w);
    *(bf8*)&s_a[swz128(row, lr*8)] = o;
  }
  __syncthreads();

  bf8 af[4];
  #pragma unroll
  for (int ks=0;ks<4;ks++) af[ks] = *(const bf8*)&s_a[swz128(wm*16+lr, ks*32 + lg*8)];
  for (int ntb=0; ntb<4; ntb++){
    f32x4 acc[8];
    #pragma unroll
    for (int q8=0;q8<8;q8++){
      acc[q8] = zero_f4();
      #pragma unroll
      for (int ks=0;ks<4;ks++){
        int ocol = ntb*128 + q8*16 + lr;
        bf8 bfr = *(const bf8*)(wf1 + (size_t)ocol*128 + ks*32 + lg*8);
        acc[q8] = MFMA(af[ks], bfr, acc[q8]);
      }
    }
    #pragma unroll
    for (int q8=0;q8<8;q8++){
      int col = ntb*128 + q8*16 + lr;
      float bb = fc1b[col];
      #pragma unroll
      for (int j=0;j<4;j++){
        int tl = wm*16 + lg*4 + j;
        h[(t0+tl)*512 + col] = (bf16)(acc[q8][j] + bb);
      }
    }
  }
}

// ---------------- kernel 4: dwconv3x3 + GELU + fc2 + residual ------------
// r14 structure (DMA double-buffer + counted barriers + LIFO); x1 bf16.
__global__ __launch_bounds__(256) void k_mlp2(
    const bf16* __restrict__ h, const float* __restrict__ dww, const float* __restrict__ dwb,
    const bf16* __restrict__ wf2, const float* __restrict__ fc2b,
    const bf16* __restrict__ x1, float* __restrict__ outx)
{
  __shared__ __align__(16) bf16 s_hh[2][100*128];
  int tid = threadIdx.x, wm = tid>>6, l = tid&63;
  int lr = l & 15, lg = l >> 4;
  int tile = 575 - blockIdx.x, b = 3 - blockIdx.y;   // LIFO vs producer order
  int ty = tile / 24, tx = tile % 24;
  int cq = (tid & 31) * 4;     // channel quad
  int tg2 = tid >> 5;          // output row iy (0..7)

  f32x4 acc[8];
  #pragma unroll
  for (int q=0;q<8;q++) acc[q] = zero_f4();

  bool edge = (ty==0) | (ty==23) | (tx==0) | (tx==23);
  if (edge){
    #pragma unroll
    for (int it=0; it<7; it++){
      int idx = it*256 + tid;
      if (idx < 1600){
        int pos = idx>>4, c0 = (idx&15)*8;
        int hy = pos/10, hx = pos%10;
        int yy = ty*8 + hy - 1, xx = tx*8 + hx - 1;
        if (yy<0 || yy>=IMG || xx<0 || xx>=IMG){
          *(bf8*)&s_hh[0][pos*128 + c0] = zero_bf8();
          *(bf8*)&s_hh[1][pos*128 + c0] = zero_bf8();
        }
      }
    }
  }

  #define STAGE_DMA(KC, BUF)                                                  \
    _Pragma("unroll")                                                         \
    for (int it=0; it<7; it++){                                               \
      int idx = it*256 + tid;                                                 \
      if (idx < 1600){                                                        \
        int pos = idx>>4, c0 = (idx&15)*8;                                    \
        int hy = pos/10, hx = pos%10;                                         \
        int yy = ty*8 + hy - 1, xx = tx*8 + hx - 1;                           \
        bf16* lb = &s_hh[BUF][it*2048 + wm*512];  /* wave-uniform base */     \
        if (yy>=0 && yy<IMG && xx>=0 && xx<IMG)                               \
          gload16(h + ((size_t)b*HW + yy*IMG + xx)*512 + (KC)*128 + c0, lb);  \
      }                                                                       \
    }

  STAGE_DMA(0, 0);
  BAR_ALL;                     // buf0 staged (+zeros visible)

  int cur = 0;
  for (int kc=0;kc<4;kc++){
    if (kc < 3) STAGE_DMA(kc+1, cur^1);   // async into the free buffer

    int chg0 = kc*128 + cq;
    float4 bias4 = *(const float4*)(dwb + chg0);
    float cr[8][4];
    #pragma unroll
    for (int i=0;i<8;i++){ cr[i][0]=bias4.x; cr[i][1]=bias4.y; cr[i][2]=bias4.z; cr[i][3]=bias4.w; }
    #pragma unroll
    for (int dy=0;dy<3;dy++){
      float rv[10][4];
      #pragma unroll
      for (int p=0;p<10;p++){
        bf4 pv = *(const bf4*)&s_hh[cur][((tg2+dy)*10 + p)*128 + cq];
        rv[p][0]=(float)pv[0]; rv[p][1]=(float)pv[1];
        rv[p][2]=(float)pv[2]; rv[p][3]=(float)pv[3];
      }
      #pragma unroll
      for (int dx=0;dx<3;dx++){
        int tq = dy*3+dx;
        float w0 = dww[(chg0+0)*9 + tq];
        float w1 = dww[(chg0+1)*9 + tq];
        float w2 = dww[(chg0+2)*9 + tq];
        float w3 = dww[(chg0+3)*9 + tq];
        #pragma unroll
        for (int i=0;i<8;i++){
          cr[i][0] += rv[i+dx][0]*w0;
          cr[i][1] += rv[i+dx][1]*w1;
          cr[i][2] += rv[i+dx][2]*w2;
          cr[i][3] += rv[i+dx][3]*w3;
        }
      }
    }
    bf4 gout[8];
    #pragma unroll
    for (int i=0;i<8;i++){
      #pragma unroll
      for (int c=0;c<4;c++){
        float hv = cr[i][c];
        float hv2 = hv*hv;
        float v = hv * fmaf(hv2, -0.0713548353f, -1.5957691216f);
        float g = hv * __builtin_amdgcn_rcpf(1.0f + __expf(v));
        gout[i][c] = (bf16)g;
      }
    }
    BAR_LGKM;                  // conv reads done; DMA stays in flight
    #pragma unroll
    for (int i=0;i<8;i++){
      int pos = (tg2+1)*10 + (i+1);
      *(bf4*)&s_hh[cur][pos*128 + (cq ^ (i<<3))] = gout[i];
    }
    {
      bf8 af[4];
      #pragma unroll
      for (int ks=0;ks<4;ks++){
        int tok = wm*16 + lr;
        int pos = ((tok>>3)+1)*10 + (tok&7) + 1;
        af[ks] = *(const bf8*)&s_hh[cur][pos*128 + ((ks*32 + lg*8) ^ ((lr&7)<<3))];
      }
      #pragma unroll
      for (int q=0;q<8;q++){
        #pragma unroll
        for (int ks=0;ks<4;ks++){
          bf8 bfr = *(const bf8*)(wf2 + (size_t)(q*16+lr)*512 + kc*128 + ks*32 + lg*8);
          acc[q] = MFMA(af[ks], bfr, acc[q]);
        }
      }
    }
    BAR_ALL;                   // fc2 reads done + next buffer's DMA landed
    cur ^= 1;
  }
  #pragma unroll
  for (int q=0;q<8;q++){
    int col = q*16 + lr;
    float bb = fc2b[col];
    #pragma unroll
    for (int j=0;j<4;j++){
      int tok = wm*16 + lg*4 + j;
      int yy = ty*8 + (tok>>3), xx = tx*8 + (tok&7);
      size_t addr = ((size_t)b*HW + yy*IMG + xx)*128 + col;
      outx[addr] = acc[q][j] + bb + (float)x1[addr];
    }
  }
  #undef STAGE_DMA
}

// ---------------- launcher ----------------
extern "C" void kernel_launch(void* const* d_in, const int* in_sizes, int n_in,
                              void* d_out, int out_size, void* d_ws, size_t ws_size,
                              hipStream_t stream)
{
  const float* x      = (const float*)d_in[0];
  const float* cor    = (const float*)d_in[1];
  const float* q_w    = (const float*)d_in[2];
  const float* kv_w   = (const float*)d_in[3];
  const float* cor_w  = (const float*)d_in[4];
  const float* proj_w = (const float*)d_in[5];
  const float* proj_b = (const float*)d_in[6];
  const float* mproj_w= (const float*)d_in[7];
  const float* mproj_b= (const float*)d_in[8];
  const float* n1w    = (const float*)d_in[9];
  const float* n1b    = (const float*)d_in[10];
  const float* n2w    = (const float*)d_in[11];
  const float* n2b    = (const float*)d_in[12];
  const float* fc1w   = (const float*)d_in[13];
  const float* fc1b   = (const float*)d_in[14];
  const float* dww    = (const float*)d_in[15];
  const float* dwb    = (const float*)d_in[16];
  const float* fc2w   = (const float*)d_in[17];
  const float* fc2b   = (const float*)d_in[18];
  float* out = (float*)d_out;

  char* ws = (char*)d_ws;
  bf16* wq   = (bf16*)(ws + 0);          // 32768
  bf16* wkv  = (bf16*)(ws + 32768);      // 65536
  bf16* wpj  = (bf16*)(ws + 98304);      // 32768
  bf16* a2w  = (bf16*)(ws + 131072);     // 8192
  bf16* wf1  = (bf16*)(ws + 139264);     // 131072
  bf16* wf2  = (bf16*)(ws + 270336);     // 131072
  bf16* x1   = (bf16*)(ws + 401408);     // 37748736 (bf16 now)
  bf16* hbuf = (bf16*)(ws + 401408 + 37748736);  // 150994944

  k_prep<<<784, 256, 0, stream>>>(q_w, kv_w, proj_w, fc1w, fc2w, mproj_w, cor_w,
                                  wq, wkv, wpj, wf1, wf2, a2w);

  k_attn<<<NWB,      256, 0, stream>>>(x, cor, n1w, n1b, wq, wkv, wpj, a2w,
                                       proj_b, mproj_b,
                                       x1, out + (size_t)T_TOT*128);
  k_fc1 <<<T_TOT/64, 256, 0, stream>>>(x1, n2w, n2b, wf1, fc1b, hbuf);
  k_mlp2<<<dim3(576,4), 256, 0, stream>>>(hbuf, dww, dwb, wf2, fc2b, x1, out);
}